// Round 13
// baseline (137.694 us; speedup 1.0000x reference)
//
#include <hip/hip_runtime.h>
#include <math.h>

#define NPTS 200
#define NCH  13
#define BLK  256
#define FPB  (NPTS * NCH)          // 2600 floats per batch

// 4-byte-aligned float4 for dword-aligned (not 16B-aligned) vector loads
typedef float f4u __attribute__((ext_vector_type(4), aligned(4)));

#define ACCUMULATE(Q0,Q1,Q2,Q3,Q4,Q5,Q6,Q7,Q8,Q9,Q10,Q11,Q12)               \
    {                                                                        \
        float wt = aa * (Q0) + bb;                                           \
        wt = fmaxf(wt, 0.f) + 1e-8f;                                         \
        const float v1x = fmaf(shift, (Q7),  (Q1));                          \
        const float v1y = fmaf(shift, (Q8),  (Q2));                          \
        const float v1z = fmaf(shift, (Q9),  (Q3));                          \
        const float v2x = fmaf(shift, (Q10), (Q4));                          \
        const float v2y = fmaf(shift, (Q11), (Q5));                          \
        const float v2z = fmaf(shift, (Q12), (Q6));                          \
        const float wv2x = wt * v2x, wv2y = wt * v2y, wv2z = wt * v2z;       \
        acc[0] += wt;                                                        \
        acc[1] += wt * v1x; acc[2] += wt * v1y; acc[3] += wt * v1z;          \
        acc[4] += wv2x;     acc[5] += wv2y;     acc[6] += wv2z;              \
        acc[7]  += wv2x * v1x; acc[8]  += wv2x * v1y; acc[9]  += wv2x * v1z; \
        acc[10] += wv2y * v1x; acc[11] += wv2y * v1y; acc[12] += wv2y * v1z; \
        acc[13] += wv2z * v1x; acc[14] += wv2z * v1y; acc[15] += wv2z * v1z; \
    }

// Branchless symmetric 4x4 Jacobi rotation on pair (P,Q) — HW-verified in
// v6/v7/v8 at absmax 0.015625. apq==0 => identity rotation; NaN killed by
// the select.
#define ROTB(dp, dq, opq, e1p, e1q, e2p, e2q, P, Q)                          \
    {                                                                        \
        const float apq = opq;                                               \
        const float tau = (dq - dp) * 0.5f * __builtin_amdgcn_rcpf(apq);     \
        float tt = copysignf(1.0f, tau) * __builtin_amdgcn_rcpf(             \
                     fabsf(tau) +                                            \
                     __builtin_amdgcn_sqrtf(fmaf(tau, tau, 1.0f)));          \
        tt = (apq != 0.0f) ? tt : 0.0f;                                      \
        const float c = __builtin_amdgcn_rsqf(fmaf(tt, tt, 1.0f));           \
        const float s = tt * c;                                              \
        dp -= tt * apq;                                                      \
        dq += tt * apq;                                                      \
        opq = 0.0f;                                                         \
        { const float t1 = e1p; e1p = c * t1 - s * e1q;                      \
          e1q = s * t1 + c * e1q; }                                          \
        { const float t2 = e2p; e2p = c * t2 - s * e2q;                      \
          e2q = s * t2 + c * e2q; }                                          \
        _Pragma("unroll")                                                    \
        for (int k = 0; k < 4; ++k) {                                        \
            const float a1 = Vm[k][P], a2 = Vm[k][Q];                        \
            Vm[k][P] = c * a1 - s * a2;                                      \
            Vm[k][Q] = s * a1 + c * a2;                                      \
        }                                                                    \
    }

// ---------------------------------------------------------------------------
// Fused v11: v8 (quarter-wave packing, best-equal) + WAVE-PRIVATE LDS STORE
// REPACK. The one untested counter anomaly: every kernel dispatch with full
// counters showed WRITE_SIZE ~3x the 19.7MB output (58-75MB) — consistent
// with 12B/lane f3s stores costing full 32B HBM sectors (32/12 ~= 2.7-3x).
// Fix: lanes write results to a wave-private LDS region (4 x 9600B = 38.4KB,
// free at the grid-capped 2 blocks/CU), then the wave stores its 4
// CONTIGUOUS batches as 16B-aligned float4 — 1KB/instr, every sector fully
// covered. Same-wave cross-lane LDS without barrier is HW-verified (v2).
// Everything through R,t is v8 byte-for-byte (absmax 0.015625 verified).
// Zero barriers, zero cross-wave communication.
// ---------------------------------------------------------------------------
__global__ __launch_bounds__(BLK, 2) void fused_kernel(
    const float* __restrict__ net_in,   // (B, 200, 13)
    const float* __restrict__ shift_p,
    const float* __restrict__ a_p,
    const float* __restrict__ b_p,
    float* __restrict__ out)            // (B, 200, 3)
{
    __shared__ float s_out[4][2400];      // per-wave out staging (38,400 B)

    const int tid = threadIdx.x;
    const int w   = tid >> 6;             // wave id in block
    const int l   = tid & 63;
    const int t   = l & 15;               // lane within quarter
    const int g   = l >> 4;               // quarter index
    const int b   = (blockIdx.x * 4 + w) * 4 + g;  // per-quarter batch

    const float shift = shift_p[0];
    const float aa    = a_p[0];
    const float bb    = b_p[0];

    const float* src = net_in + (size_t)b * FPB;

    // ---- per-lane accumulation: 16 lanes per batch, 200 = 12*16 + 8 ----
    float acc[16];
    #pragma unroll
    for (int k = 0; k < 16; ++k) acc[k] = 0.f;

    float sx2[13], sy2[13], sz2[13];

    #pragma unroll
    for (int i = 0; i < 13; ++i) {
        if (i < 12 || t < 8) {            // i<12 always valid; i==12 only t<8
            const float* q = src + (t + 16 * i) * NCH;
            const f4u v0 = *(const f4u*)(q);      // w, x1,y1,z1
            const f4u v1 = *(const f4u*)(q + 4);  // x2,y2,z2, n1x
            const f4u v2 = *(const f4u*)(q + 8);  // n1y,n1z, n2x,n2y
            const float q12 = q[12];              // n2z
            ACCUMULATE(v0.x, v0.y, v0.z, v0.w,
                       v1.x, v1.y, v1.z, v1.w,
                       v2.x, v2.y, v2.z, v2.w, q12)
            sx2[i] = v1.x; sy2[i] = v1.y; sz2[i] = v1.z;
        } else {
            sx2[i] = 0.f; sy2[i] = 0.f; sz2[i] = 0.f;
        }
    }

    // ---- 4-level xor-butterfly within each 16-lane quarter ----
    #pragma unroll
    for (int k = 0; k < 16; ++k) {
        acc[k] += __shfl_xor(acc[k],  8, 64);
        acc[k] += __shfl_xor(acc[k],  4, 64);
        acc[k] += __shfl_xor(acc[k],  2, 64);
        acc[k] += __shfl_xor(acc[k],  1, 64);
    }

    // ---- centroids and centered covariance S (per quarter) ----
    const float W = acc[0];
    const float invW = __builtin_amdgcn_rcpf(W);
    const float v1cx = acc[1] * invW, v1cy = acc[2] * invW, v1cz = acc[3] * invW;
    const float v2cx = acc[4] * invW, v2cy = acc[5] * invW, v2cz = acc[6] * invW;

    const float Sxx = acc[7]  - W * v2cx * v1cx;
    const float Sxy = acc[8]  - W * v2cx * v1cy;
    const float Sxz = acc[9]  - W * v2cx * v1cz;
    const float Syx = acc[10] - W * v2cy * v1cx;
    const float Syy = acc[11] - W * v2cy * v1cy;
    const float Syz = acc[12] - W * v2cy * v1cz;
    const float Szx = acc[13] - W * v2cz * v1cx;
    const float Szy = acc[14] - W * v2cz * v1cy;
    const float Szz = acc[15] - W * v2cz * v1cz;

    // ---- Horn K matrix in symmetric storage (diag d0..d3, off oPQ) ----
    float d0  = Sxx + Syy + Szz;
    float o01 = Syz - Szy;
    float o02 = Szx - Sxz;
    float o03 = Sxy - Syx;
    float d1  = Sxx - Syy - Szz;
    float o12 = Sxy + Syx;
    float o13 = Szx + Sxz;
    float d2  = -Sxx + Syy - Szz;
    float o23 = Syz + Szy;
    float d3  = -Sxx - Syy + Szz;

    float Vm[4][4] = {{1,0,0,0},{0,1,0,0},{0,0,1,0},{0,0,0,1}};

    // 4 sweeps x 6 branchless symmetric rotations (once per 4 batches)
    for (int sweep = 0; sweep < 4; ++sweep) {
        ROTB(d0, d1, o01,  o02, o12,  o03, o13,  0, 1)
        ROTB(d0, d2, o02,  o01, o12,  o03, o23,  0, 2)
        ROTB(d0, d3, o03,  o01, o13,  o02, o23,  0, 3)
        ROTB(d1, d2, o12,  o01, o02,  o13, o23,  1, 2)
        ROTB(d1, d3, o13,  o01, o03,  o12, o23,  1, 3)
        ROTB(d2, d3, o23,  o02, o03,  o12, o13,  2, 3)
    }

    // ---- best eigenvector: branchless compare chain (per-lane data) ----
    float bd = d0;
    float q0 = Vm[0][0], qx = Vm[1][0], qy = Vm[2][0], qz = Vm[3][0];
    { const bool c1 = d1 > bd;
      bd = c1 ? d1 : bd;
      q0 = c1 ? Vm[0][1] : q0; qx = c1 ? Vm[1][1] : qx;
      qy = c1 ? Vm[2][1] : qy; qz = c1 ? Vm[3][1] : qz; }
    { const bool c2 = d2 > bd;
      bd = c2 ? d2 : bd;
      q0 = c2 ? Vm[0][2] : q0; qx = c2 ? Vm[1][2] : qx;
      qy = c2 ? Vm[2][2] : qy; qz = c2 ? Vm[3][2] : qz; }
    { const bool c3 = d3 > bd;
      q0 = c3 ? Vm[0][3] : q0; qx = c3 ? Vm[1][3] : qx;
      qy = c3 ? Vm[2][3] : qy; qz = c3 ? Vm[3][3] : qz; }

    // renormalize (approx rotations leave ~1e-5 norm drift)
    const float qn = __builtin_amdgcn_rsqf(q0*q0 + qx*qx + qy*qy + qz*qz);
    q0 *= qn; qx *= qn; qy *= qn; qz *= qn;

    const float R00 = q0*q0 + qx*qx - qy*qy - qz*qz;
    const float R01 = 2.0f * (qx*qy - q0*qz);
    const float R02 = 2.0f * (qx*qz + q0*qy);
    const float R10 = 2.0f * (qx*qy + q0*qz);
    const float R11 = q0*q0 - qx*qx + qy*qy - qz*qz;
    const float R12 = 2.0f * (qy*qz - q0*qx);
    const float R20 = 2.0f * (qx*qz - q0*qy);
    const float R21 = 2.0f * (qy*qz + q0*qx);
    const float R22 = q0*q0 - qx*qx - qy*qy + qz*qz;

    const float tx = v1cx - (R00 * v2cx + R01 * v2cy + R02 * v2cz);
    const float ty = v1cy - (R10 * v2cx + R11 * v2cy + R12 * v2cz);
    const float tz = v1cz - (R20 * v2cx + R21 * v2cy + R22 * v2cz);

    // ---- apply: results -> wave-private LDS (12B/lane, ~2-way banks) ----
    float* so = &s_out[w][0];
    #pragma unroll
    for (int i = 0; i < 13; ++i) {
        if (i < 12 || t < 8) {
            const int p = t + 16 * i;
            const float X = sx2[i], Y = sy2[i], Z = sz2[i];
            const int o = g * 600 + p * 3;
            so[o]     = R00 * X + R01 * Y + R02 * Z + tx;
            so[o + 1] = R10 * X + R11 * Y + R12 * Z + ty;
            so[o + 2] = R20 * X + R21 * Y + R22 * Z + tz;
        }
    }
    // same wave, in-order DS pipe (HW-verified pattern, v2): no barrier.
    __asm__ __volatile__("" ::: "memory");

    // ---- cooperative store: 4 contiguous batches = 9600B, 16B-aligned,
    //      600 float4 = 9 full rounds + 24-lane tail, 1KB/instruction ----
    const float4* sv = (const float4*)so;
    float4* og = (float4*)(out + (size_t)((blockIdx.x * 4 + w) * 4) * (NPTS * 3));
    #pragma unroll
    for (int j = 0; j < 9; ++j) {
        og[j * 64 + l] = sv[j * 64 + l];
    }
    if (l < 24) {
        og[576 + l] = sv[576 + l];
    }
}

extern "C" void kernel_launch(void* const* d_in, const int* in_sizes, int n_in,
                              void* d_out, int out_size, void* d_ws, size_t ws_size,
                              hipStream_t stream) {
    const float* net_in  = (const float*)d_in[0];
    const float* shift_p = (const float*)d_in[1];
    const float* a_p     = (const float*)d_in[2];
    const float* b_p     = (const float*)d_in[3];
    float* out = (float*)d_out;

    const int B = in_sizes[0] / FPB;             // 8192
    (void)d_ws; (void)ws_size; (void)n_in; (void)out_size;

    // 16 batches per block (4 waves x 4 quarter-wave batches) -> 512 blocks
    fused_kernel<<<B / 16, BLK, 0, stream>>>(net_in, shift_p, a_p, b_p, out);
}